// Round 4
// baseline (1879.886 us; speedup 1.0000x reference)
//
#include <hip/hip_runtime.h>

typedef _Float16 half_t;
typedef _Float16 half4_t __attribute__((ext_vector_type(4)));
typedef _Float16 half8_t __attribute__((ext_vector_type(8)));
typedef float float4_t __attribute__((ext_vector_type(4)));

#define S_LEN 4096
#define NB 4
#define H_DIM 1024

#define MFMA16(a, b, c) __builtin_amdgcn_mfma_f32_16x16x32_f16(a, b, c, 0, 0, 0)

// LDS-only barrier (guide-verified m201 pattern): wait local (LDS) ops, then
// the compiler-visible barrier builtin. Global loads stay in flight across it.
#define BAR_LDS()                                      \
  do {                                                 \
    asm volatile("s_waitcnt lgkmcnt(0)" ::: "memory"); \
    __builtin_amdgcn_s_barrier();                      \
  } while (0)

// ---------------------------------------------------------------------------
// Kernel 0: transpose + fp16-split W -> Wt_hi/Wt_lo [h][f] (scratch in d_out;
// flash_attn overwrites all of d_out afterwards).
// ---------------------------------------------------------------------------
__global__ __launch_bounds__(256) void wt_prep(
    const float* __restrict__ Wq, const float* __restrict__ Wk,
    const float* __restrict__ Wv, half_t* __restrict__ wth,
    half_t* __restrict__ wtl) {
  const int zi = blockIdx.z;
  const float* W = (zi == 0) ? Wq : (zi == 1) ? Wk : Wv;
  half_t* oh = wth + (size_t)zi * H_DIM * H_DIM;
  half_t* ol = wtl + (size_t)zi * H_DIM * H_DIM;
  const int h0 = blockIdx.x * 32, f0 = blockIdx.y * 32;
  __shared__ float Ws[32][33];
  const int t = threadIdx.x;
  const int c = t & 31, r8 = t >> 5;
#pragma unroll
  for (int rr = 0; rr < 4; rr++)
    Ws[r8 * 4 + rr][c] = W[(size_t)(f0 + r8 * 4 + rr) * H_DIM + h0 + c];
  __syncthreads();
#pragma unroll
  for (int rr = 0; rr < 4; rr++) {
    int h = r8 * 4 + rr;
    float v = Ws[c][h];
    half_t hi = (half_t)v;
    half_t lo = (half_t)(v - (float)hi);
    oh[(size_t)(h0 + h) * H_DIM + f0 + c] = hi;
    ol[(size_t)(h0 + h) * H_DIM + f0 + c] = lo;
  }
}

// ---------------------------------------------------------------------------
// Kernel 1: QKV projection on MFMA, 3-term fp16 split (hh + lh + hl).
// (unchanged)
// ---------------------------------------------------------------------------
#define QKV_BK 64

__global__ __launch_bounds__(256, 2) void qkv_mfma(
    const float* __restrict__ x, const half_t* __restrict__ wth,
    const half_t* __restrict__ wtl, const float* __restrict__ bq,
    const float* __restrict__ bk, const float* __restrict__ bv,
    half_t* __restrict__ ws) {
  const int zi = blockIdx.z;
  const half_t* Ah_g = wth + (size_t)zi * H_DIM * H_DIM;
  const half_t* Al_g = wtl + (size_t)zi * H_DIM * H_DIM;
  const float* bias = (zi == 0) ? bq : (zi == 1) ? bk : bv;
  half_t* out = ws + (size_t)zi * ((size_t)NB * S_LEN * H_DIM);
  const int m0 = blockIdx.x * 128;  // h
  const int n0 = blockIdx.y * 128;  // flattened b*s
  const int t = threadIdx.x;
  const int w = t >> 6, lane = t & 63, ln = lane & 15, quad = lane >> 4;

  __shared__ half_t Bs[16384];

  float4_t acc[2][8] = {};

  const int ss = t >> 1;
  const int fh = (t & 1) * 32;
  const int snt = ss >> 4, sln = ss & 15;

  for (int k0 = 0; k0 < H_DIM; k0 += QKV_BK) {
    half8_t ah[2][2], al[2][2];
#pragma unroll
    for (int i = 0; i < 2; i++) {
      const size_t arow =
          (size_t)(m0 + w * 32 + i * 16 + ln) * H_DIM + k0 + quad * 8;
#pragma unroll
      for (int k2 = 0; k2 < 2; k2++) {
        ah[i][k2] = *(const half8_t*)(Ah_g + arow + k2 * 32);
        al[i][k2] = *(const half8_t*)(Al_g + arow + k2 * 32);
      }
    }
    __syncthreads();
    {
      const float* xp = x + (size_t)(n0 + ss) * H_DIM + k0 + fh;
#pragma unroll
      for (int g = 0; g < 4; g++) {
        float4 v0 = *(const float4*)(xp + g * 8);
        float4 v1 = *(const float4*)(xp + g * 8 + 4);
        float vv[8] = {v0.x, v0.y, v0.z, v0.w, v1.x, v1.y, v1.z, v1.w};
        half8_t hhi, hlo;
#pragma unroll
        for (int j = 0; j < 8; j++) {
          half_t h = (half_t)vv[j];
          hhi[j] = h;
          hlo[j] = (half_t)(vv[j] - (float)h);
        }
        int f = fh + g * 8;
        int k2 = f >> 5, qd = (f >> 3) & 3;
        int base = ((k2 * 8 + snt) * 64 + qd * 16 + sln) * 8;
        *(half8_t*)&Bs[base] = hhi;
        *(half8_t*)&Bs[8192 + base] = hlo;
      }
    }
    __syncthreads();
#pragma unroll
    for (int k2 = 0; k2 < 2; k2++) {
#pragma unroll
      for (int nt = 0; nt < 8; nt++) {
        int base = ((k2 * 8 + nt) * 64 + lane) * 8;
        half8_t bh = *(const half8_t*)&Bs[base];
        half8_t bl = *(const half8_t*)&Bs[8192 + base];
        acc[0][nt] = MFMA16(ah[0][k2], bh, acc[0][nt]);
        acc[1][nt] = MFMA16(ah[1][k2], bh, acc[1][nt]);
        acc[0][nt] = MFMA16(al[0][k2], bh, acc[0][nt]);
        acc[1][nt] = MFMA16(al[1][k2], bh, acc[1][nt]);
        acc[0][nt] = MFMA16(ah[0][k2], bl, acc[0][nt]);
        acc[1][nt] = MFMA16(ah[1][k2], bl, acc[1][nt]);
      }
    }
  }

  const float oscale = (zi == 0) ? 0.03125f : 1.0f;
  float bb[2][4];
#pragma unroll
  for (int i = 0; i < 2; i++)
#pragma unroll
    for (int r = 0; r < 4; r++)
      bb[i][r] = bias[m0 + w * 32 + i * 16 + quad * 4 + r];

  if (zi < 2) {
#pragma unroll
    for (int i = 0; i < 2; i++)
#pragma unroll
      for (int nt = 0; nt < 8; nt++) {
        half4_t h4;
#pragma unroll
        for (int r = 0; r < 4; r++)
          h4[r] = (half_t)((acc[i][nt][r] + bb[i][r]) * oscale);
        size_t s = n0 + nt * 16 + ln;
        *(half4_t*)&out[s * H_DIM + m0 + w * 32 + i * 16 + quad * 4] = h4;
      }
  } else {
#pragma unroll
    for (int i = 0; i < 2; i++)
#pragma unroll
      for (int nt = 0; nt < 8; nt++) {
        int sf = n0 + nt * 16 + ln;
        int b = sf >> 12, si = sf & 4095;
#pragma unroll
        for (int r = 0; r < 4; r++) {
          int h = m0 + w * 32 + i * 16 + quad * 4 + r;
          out[((size_t)b * H_DIM + h) * S_LEN + si] =
              (half_t)(acc[i][nt][r] + bb[i][r]);
        }
      }
  }
}

// ---------------------------------------------------------------------------
// Kernel 2: MFMA flash attention, TQ=64 (512 threads, 8 waves, 1 block/CU).
// This round: cross-tile software pipeline — phase C(i) (PV) is FUSED with
// phase A(i+1) (QK^T) in one 32-step loop (4 PV-MFMAs + 4 QK-MFMAs + 1
// V-load + 1 K-load per step). Per-step time doubles, so the 6-deep K ring /
// 4-deep V ring cover 2x the load latency, and each stream's stalls hide
// under the other's MFMAs. Zero extra registers: the S accumulator is dead
// after softmax, so A(i+1) reuses it. Barriers W1/W2 already order all
// Ps/wmax/wl hazards across the fused structure (still 2 barriers/iter).
// LDS: Qs 128 KB + Ps 16 KB + wmax/wl 4 KB.
// ---------------------------------------------------------------------------
#define TQ 64
#define TK 128

__global__ __launch_bounds__(512, 2) void flash_attn(
    const half_t* __restrict__ qw, const half_t* __restrict__ kw,
    const half_t* __restrict__ vt, float* __restrict__ out) {
  // batch -> 2 XCDs; 32 blocks/XCD share one K/V stream, 1 block/CU.
  const int slot = blockIdx.x & 7;
  const int b = slot >> 1;
  const int qb = ((blockIdx.x >> 3) << 1) | (slot & 1);
  const int q0 = qb * TQ;
  const int t = threadIdx.x;
  const int w = t >> 6;
  const int lane = t & 63;
  const int ln = lane & 15;
  const int quad = lane >> 4;

  __shared__ half_t Qs[65536];  // [rs(4)][ks(32)][lane(64)][8] = 128 KB
  __shared__ half_t Ps[8192];   // [rs(4)][kc(4)][lane(64)][8] = 16 KB
  __shared__ float wmax[8][64];
  __shared__ float wl[8][64];

  const half_t* qp = qw + ((size_t)b * S_LEN + q0) * H_DIM;
  const half_t* kbp = kw + (size_t)b * S_LEN * H_DIM;
  const half_t* vbt = vt + (size_t)b * H_DIM * S_LEN;

  // K ring prologue for tile 0 (issued before Q staging so it lands early)
  const half_t* kr = kbp + (size_t)(w * 16 + ln) * H_DIM + quad * 8;
  half8_t kbuf[6];
#pragma unroll
  for (int d = 0; d < 6; d++) kbuf[d] = *(const half8_t*)(kr + d * 32);

  // stage Q tile into fragment order
#pragma unroll
  for (int i = 0; i < 16; i++) {
    int flat = t * 8 + i * 4096;
    int r = flat >> 10, c = flat & 1023;
    int rs = r >> 4, lq = r & 15, ks = c >> 5, qd = (c >> 3) & 3;
    *(half8_t*)&Qs[((rs * 32 + ks) * 64 + qd * 16 + lq) * 8] =
        *(const half8_t*)&qp[(size_t)r * H_DIM + c];
  }
  BAR_LDS();

  // per-lane softmax running state, lane <-> q row (all waves redundant)
  float m_l = -1e30f;
  float l_l = 0.0f;

  float4_t O[4][8] = {};  // [rs(4 row-tiles)][j(8 col-tiles in h-chunk w)]
  float4_t s[4] = {};     // S accumulator; reused by A(i+1) after softmax(i)

  // ---------------- standalone A(0): S = Q . K^T for tile 0 ----------------
  __builtin_amdgcn_s_setprio(1);
#pragma unroll
  for (int ks = 0; ks < 32; ks++) {
    half8_t a0 = *(const half8_t*)&Qs[(ks * 64 + lane) * 8];
    half8_t a1 = *(const half8_t*)&Qs[16384 + (ks * 64 + lane) * 8];
    half8_t a2 = *(const half8_t*)&Qs[32768 + (ks * 64 + lane) * 8];
    half8_t a3 = *(const half8_t*)&Qs[49152 + (ks * 64 + lane) * 8];
    half8_t kc = kbuf[ks % 6];
    if (ks < 26) kbuf[ks % 6] = *(const half8_t*)(kr + (ks + 6) * 32);
    s[0] = MFMA16(a0, kc, s[0]);
    s[1] = MFMA16(a1, kc, s[1]);
    s[2] = MFMA16(a2, kc, s[2]);
    s[3] = MFMA16(a3, kc, s[3]);
  }
  __builtin_amdgcn_s_setprio(0);
  // reload ring with first 6 of tile 1 (in flight across softmax(0))
  kr += (size_t)TK * H_DIM;
#pragma unroll
  for (int d = 0; d < 6; d++) kbuf[d] = *(const half8_t*)(kr + d * 32);

  for (int kt = 0; kt < S_LEN; kt += TK) {
    const bool notlast = (kt + TK < S_LEN);

    // V ring preload (j=0..3 of kc=0) — in flight across softmax
    const half_t* vbase = vbt + (size_t)(w * 128 + ln) * S_LEN + kt + quad * 8;
    half8_t vr[4];
#pragma unroll
    for (int j = 0; j < 4; j++)
      vr[j] = *(const half8_t*)(vbase + (size_t)j * 16 * S_LEN);

    // ---------------- softmax stats ----------------
    // s[rs][r]: row q = rs*16 + quad*4 + r, col = w*16 + ln.
    float rm[4][4];
#pragma unroll
    for (int rs = 0; rs < 4; rs++)
#pragma unroll
      for (int r = 0; r < 4; r++) rm[rs][r] = s[rs][r];
#pragma unroll
    for (int off = 1; off < 16; off <<= 1)
#pragma unroll
      for (int rs = 0; rs < 4; rs++)
#pragma unroll
        for (int r = 0; r < 4; r++)
          rm[rs][r] = fmaxf(rm[rs][r], __shfl_xor(rm[rs][r], off));
    if (ln == 0)
#pragma unroll
      for (int rs = 0; rs < 4; rs++)
#pragma unroll
        for (int r = 0; r < 4; r++)
          wmax[w][rs * 16 + quad * 4 + r] = rm[rs][r];
    BAR_LDS();  // W1

    // every wave redundantly updates running max for q = lane
    float nm_l = m_l;
#pragma unroll
    for (int w2 = 0; w2 < 8; w2++) nm_l = fmaxf(nm_l, wmax[w2][lane]);
    float aS_l = __expf(m_l - nm_l);
    m_l = nm_l;

    // ---- P = exp(S - m) -> Ps (fragment order), O rescale fused ----
    const int pbase = (w >> 1) * 512 + (w & 1) * 256 + (ln >> 3) * 128 +
                      quad * 32 + (ln & 7);
    float pl[4][4];
#pragma unroll
    for (int rs = 0; rs < 4; rs++)
#pragma unroll
      for (int r = 0; r < 4; r++) {
        const int q = rs * 16 + quad * 4 + r;
        float nmq = __shfl(m_l, q);
        float aq = __shfl(aS_l, q);
        float p = __expf(s[rs][r] - nmq);
        pl[rs][r] = p;
        Ps[pbase + rs * 2048 + r * 8] = (half_t)p;
#pragma unroll
        for (int j = 0; j < 8; j++) O[rs][j][r] *= aq;
      }
#pragma unroll
    for (int off = 1; off < 16; off <<= 1)
#pragma unroll
      for (int rs = 0; rs < 4; rs++)
#pragma unroll
        for (int r = 0; r < 4; r++) pl[rs][r] += __shfl_xor(pl[rs][r], off);
    if (ln == 0)
#pragma unroll
      for (int rs = 0; rs < 4; rs++)
#pragma unroll
        for (int r = 0; r < 4; r++)
          wl[w][rs * 16 + quad * 4 + r] = pl[rs][r];
    BAR_LDS();  // W2

    // every wave redundantly updates running denom for q = lane
    float s8_l = 0.f;
#pragma unroll
    for (int w2 = 0; w2 < 8; w2++) s8_l += wl[w2][lane];
    l_l = l_l * aS_l + s8_l;

    // ------- fused: C(kt) = O += P @ V  (+)  A(kt+TK) = S' = Q . K^T -------
    // s is dead (consumed by softmax above) -> reuse as A(i+1) accumulator.
    if (notlast) {
      s[0] = (float4_t){0.f, 0.f, 0.f, 0.f};
      s[1] = s[0];
      s[2] = s[0];
      s[3] = s[0];
      half8_t pa[4];
      __builtin_amdgcn_s_setprio(1);
#pragma unroll
      for (int u = 0; u < 32; u++) {
        const int kc2 = u >> 3, j = u & 7;
        if ((u & 7) == 0) {
#pragma unroll
          for (int rs = 0; rs < 4; rs++)
            pa[rs] = *(const half8_t*)&Ps[((rs * 4 + kc2) * 64 + lane) * 8];
        }
        // C-part V ring refill (4 ahead)
        half8_t vc = vr[j & 3];
        const int jn = j + 4;
        if (jn < 8) {
          vr[j & 3] =
              *(const half8_t*)(vbase + (size_t)jn * 16 * S_LEN + kc2 * 32);
        } else if (kc2 < 3) {
          vr[j & 3] = *(const half8_t*)(vbase + (size_t)(jn - 8) * 16 * S_LEN +
                                        (kc2 + 1) * 32);
        }
        // A-part: Q fragments + K ring (tile kt+TK)
        half8_t a0 = *(const half8_t*)&Qs[(u * 64 + lane) * 8];
        half8_t a1 = *(const half8_t*)&Qs[16384 + (u * 64 + lane) * 8];
        half8_t a2 = *(const half8_t*)&Qs[32768 + (u * 64 + lane) * 8];
        half8_t a3 = *(const half8_t*)&Qs[49152 + (u * 64 + lane) * 8];
        half8_t kk = kbuf[u % 6];
        if (u < 26) kbuf[u % 6] = *(const half8_t*)(kr + (u + 6) * 32);
        s[0] = MFMA16(a0, kk, s[0]);
        O[0][j] = MFMA16(pa[0], vc, O[0][j]);
        s[1] = MFMA16(a1, kk, s[1]);
        O[1][j] = MFMA16(pa[1], vc, O[1][j]);
        s[2] = MFMA16(a2, kk, s[2]);
        O[2][j] = MFMA16(pa[2], vc, O[2][j]);
        s[3] = MFMA16(a3, kk, s[3]);
        O[3][j] = MFMA16(pa[3], vc, O[3][j]);
      }
      __builtin_amdgcn_s_setprio(0);
      // reload ring with first 6 of the tile after next (in flight across
      // softmax(i+1)). At the penultimate tile this reads past the K region
      // into the (mapped) vt region — garbage that is never consumed.
      kr += (size_t)TK * H_DIM;
#pragma unroll
      for (int d = 0; d < 6; d++) kbuf[d] = *(const half8_t*)(kr + d * 32);
    } else {
      // last tile: C only
      half8_t pa[4];
      __builtin_amdgcn_s_setprio(1);
#pragma unroll
      for (int u = 0; u < 32; u++) {
        const int kc2 = u >> 3, j = u & 7;
        if ((u & 7) == 0) {
#pragma unroll
          for (int rs = 0; rs < 4; rs++)
            pa[rs] = *(const half8_t*)&Ps[((rs * 4 + kc2) * 64 + lane) * 8];
        }
        half8_t vc = vr[j & 3];
        const int jn = j + 4;
        if (jn < 8) {
          vr[j & 3] =
              *(const half8_t*)(vbase + (size_t)jn * 16 * S_LEN + kc2 * 32);
        } else if (kc2 < 3) {
          vr[j & 3] = *(const half8_t*)(vbase + (size_t)(jn - 8) * 16 * S_LEN +
                                        (kc2 + 1) * 32);
        }
#pragma unroll
        for (int rs = 0; rs < 4; rs++)
          O[rs][j] = MFMA16(pa[rs], vc, O[rs][j]);
      }
      __builtin_amdgcn_s_setprio(0);
    }
  }

  // ---------------- epilogue ----------------
  float il[4][4];
#pragma unroll
  for (int rs = 0; rs < 4; rs++)
#pragma unroll
    for (int r = 0; r < 4; r++)
      il[rs][r] = 1.0f / __shfl(l_l, rs * 16 + quad * 4 + r);
  float* ob = out + ((size_t)b * S_LEN + q0) * H_DIM + w * 128 + ln;
#pragma unroll
  for (int rs = 0; rs < 4; rs++)
#pragma unroll
    for (int j = 0; j < 8; j++)
#pragma unroll
      for (int r = 0; r < 4; r++)
        ob[(size_t)(rs * 16 + quad * 4 + r) * H_DIM + j * 16] =
            O[rs][j][r] * il[rs][r];
}

// ---------------------------------------------------------------------------
extern "C" void kernel_launch(void* const* d_in, const int* in_sizes, int n_in,
                              void* d_out, int out_size, void* d_ws,
                              size_t ws_size, hipStream_t stream) {
  const float* x = (const float*)d_in[0];
  const float* Wq = (const float*)d_in[1];
  const float* bq = (const float*)d_in[2];
  const float* Wk = (const float*)d_in[3];
  const float* bk = (const float*)d_in[4];
  const float* Wv = (const float*)d_in[5];
  const float* bv = (const float*)d_in[6];
  half_t* ws = (half_t*)d_ws;  // q(32MB) | k(32MB) | vt(32MB, transposed)
  float* out = (float*)d_out;

  half_t* wth = (half_t*)d_out;  // scratch; overwritten by flash_attn
  half_t* wtl = wth + (size_t)3 * H_DIM * H_DIM;

  wt_prep<<<dim3(32, 32, 3), 256, 0, stream>>>(Wq, Wk, Wv, wth, wtl);

  qkv_mfma<<<dim3(8, 128, 3), 256, 0, stream>>>(x, wth, wtl, bq, bk, bv, ws);

  const half_t* qw = ws;
  const half_t* kw = ws + (size_t)NB * S_LEN * H_DIM;
  const half_t* vt = ws + 2 * (size_t)NB * S_LEN * H_DIM;
  flash_attn<<<dim3((S_LEN / TQ) * NB), 512, 0, stream>>>(qw, kw, vt, out);
}

// Round 5
// 1134.685 us; speedup vs baseline: 1.6567x; 1.6567x over previous
//
#include <hip/hip_runtime.h>

typedef _Float16 half_t;
typedef _Float16 half4_t __attribute__((ext_vector_type(4)));
typedef _Float16 half8_t __attribute__((ext_vector_type(8)));
typedef float float4_t __attribute__((ext_vector_type(4)));

#define S_LEN 4096
#define NB 4
#define H_DIM 1024

#define MFMA16(a, b, c) __builtin_amdgcn_mfma_f32_16x16x32_f16(a, b, c, 0, 0, 0)

// LDS-only barrier (guide-verified m201 pattern): wait local (LDS) ops, then
// the compiler-visible barrier builtin. Global loads stay in flight across it.
#define BAR_LDS()                                      \
  do {                                                 \
    asm volatile("s_waitcnt lgkmcnt(0)" ::: "memory"); \
    __builtin_amdgcn_s_barrier();                      \
  } while (0)

// ---------------------------------------------------------------------------
// Kernel 0: transpose + fp16-split W -> Wt_hi/Wt_lo [h][f] (scratch in d_out;
// flash_attn overwrites all of d_out afterwards).
// ---------------------------------------------------------------------------
__global__ __launch_bounds__(256) void wt_prep(
    const float* __restrict__ Wq, const float* __restrict__ Wk,
    const float* __restrict__ Wv, half_t* __restrict__ wth,
    half_t* __restrict__ wtl) {
  const int zi = blockIdx.z;
  const float* W = (zi == 0) ? Wq : (zi == 1) ? Wk : Wv;
  half_t* oh = wth + (size_t)zi * H_DIM * H_DIM;
  half_t* ol = wtl + (size_t)zi * H_DIM * H_DIM;
  const int h0 = blockIdx.x * 32, f0 = blockIdx.y * 32;
  __shared__ float Ws[32][33];
  const int t = threadIdx.x;
  const int c = t & 31, r8 = t >> 5;
#pragma unroll
  for (int rr = 0; rr < 4; rr++)
    Ws[r8 * 4 + rr][c] = W[(size_t)(f0 + r8 * 4 + rr) * H_DIM + h0 + c];
  __syncthreads();
#pragma unroll
  for (int rr = 0; rr < 4; rr++) {
    int h = r8 * 4 + rr;
    float v = Ws[c][h];
    half_t hi = (half_t)v;
    half_t lo = (half_t)(v - (float)hi);
    oh[(size_t)(h0 + h) * H_DIM + f0 + c] = hi;
    ol[(size_t)(h0 + h) * H_DIM + f0 + c] = lo;
  }
}

// ---------------------------------------------------------------------------
// Kernel 1: QKV projection on MFMA, 3-term fp16 split (hh + lh + hl).
// (unchanged)
// ---------------------------------------------------------------------------
#define QKV_BK 64

__global__ __launch_bounds__(256, 2) void qkv_mfma(
    const float* __restrict__ x, const half_t* __restrict__ wth,
    const half_t* __restrict__ wtl, const float* __restrict__ bq,
    const float* __restrict__ bk, const float* __restrict__ bv,
    half_t* __restrict__ ws) {
  const int zi = blockIdx.z;
  const half_t* Ah_g = wth + (size_t)zi * H_DIM * H_DIM;
  const half_t* Al_g = wtl + (size_t)zi * H_DIM * H_DIM;
  const float* bias = (zi == 0) ? bq : (zi == 1) ? bk : bv;
  half_t* out = ws + (size_t)zi * ((size_t)NB * S_LEN * H_DIM);
  const int m0 = blockIdx.x * 128;  // h
  const int n0 = blockIdx.y * 128;  // flattened b*s
  const int t = threadIdx.x;
  const int w = t >> 6, lane = t & 63, ln = lane & 15, quad = lane >> 4;

  __shared__ half_t Bs[16384];

  float4_t acc[2][8] = {};

  const int ss = t >> 1;
  const int fh = (t & 1) * 32;
  const int snt = ss >> 4, sln = ss & 15;

  for (int k0 = 0; k0 < H_DIM; k0 += QKV_BK) {
    half8_t ah[2][2], al[2][2];
#pragma unroll
    for (int i = 0; i < 2; i++) {
      const size_t arow =
          (size_t)(m0 + w * 32 + i * 16 + ln) * H_DIM + k0 + quad * 8;
#pragma unroll
      for (int k2 = 0; k2 < 2; k2++) {
        ah[i][k2] = *(const half8_t*)(Ah_g + arow + k2 * 32);
        al[i][k2] = *(const half8_t*)(Al_g + arow + k2 * 32);
      }
    }
    __syncthreads();
    {
      const float* xp = x + (size_t)(n0 + ss) * H_DIM + k0 + fh;
#pragma unroll
      for (int g = 0; g < 4; g++) {
        float4 v0 = *(const float4*)(xp + g * 8);
        float4 v1 = *(const float4*)(xp + g * 8 + 4);
        float vv[8] = {v0.x, v0.y, v0.z, v0.w, v1.x, v1.y, v1.z, v1.w};
        half8_t hhi, hlo;
#pragma unroll
        for (int j = 0; j < 8; j++) {
          half_t h = (half_t)vv[j];
          hhi[j] = h;
          hlo[j] = (half_t)(vv[j] - (float)h);
        }
        int f = fh + g * 8;
        int k2 = f >> 5, qd = (f >> 3) & 3;
        int base = ((k2 * 8 + snt) * 64 + qd * 16 + sln) * 8;
        *(half8_t*)&Bs[base] = hhi;
        *(half8_t*)&Bs[8192 + base] = hlo;
      }
    }
    __syncthreads();
#pragma unroll
    for (int k2 = 0; k2 < 2; k2++) {
#pragma unroll
      for (int nt = 0; nt < 8; nt++) {
        int base = ((k2 * 8 + nt) * 64 + lane) * 8;
        half8_t bh = *(const half8_t*)&Bs[base];
        half8_t bl = *(const half8_t*)&Bs[8192 + base];
        acc[0][nt] = MFMA16(ah[0][k2], bh, acc[0][nt]);
        acc[1][nt] = MFMA16(ah[1][k2], bh, acc[1][nt]);
        acc[0][nt] = MFMA16(al[0][k2], bh, acc[0][nt]);
        acc[1][nt] = MFMA16(al[1][k2], bh, acc[1][nt]);
        acc[0][nt] = MFMA16(ah[0][k2], bl, acc[0][nt]);
        acc[1][nt] = MFMA16(ah[1][k2], bl, acc[1][nt]);
      }
    }
  }

  const float oscale = (zi == 0) ? 0.03125f : 1.0f;
  float bb[2][4];
#pragma unroll
  for (int i = 0; i < 2; i++)
#pragma unroll
    for (int r = 0; r < 4; r++)
      bb[i][r] = bias[m0 + w * 32 + i * 16 + quad * 4 + r];

  if (zi < 2) {
#pragma unroll
    for (int i = 0; i < 2; i++)
#pragma unroll
      for (int nt = 0; nt < 8; nt++) {
        half4_t h4;
#pragma unroll
        for (int r = 0; r < 4; r++)
          h4[r] = (half_t)((acc[i][nt][r] + bb[i][r]) * oscale);
        size_t s = n0 + nt * 16 + ln;
        *(half4_t*)&out[s * H_DIM + m0 + w * 32 + i * 16 + quad * 4] = h4;
      }
  } else {
#pragma unroll
    for (int i = 0; i < 2; i++)
#pragma unroll
      for (int nt = 0; nt < 8; nt++) {
        int sf = n0 + nt * 16 + ln;
        int b = sf >> 12, si = sf & 4095;
#pragma unroll
        for (int r = 0; r < 4; r++) {
          int h = m0 + w * 32 + i * 16 + quad * 4 + r;
          out[((size_t)b * H_DIM + h) * S_LEN + si] =
              (half_t)(acc[i][nt][r] + bb[i][r]);
        }
      }
  }
}

// ---------------------------------------------------------------------------
// Kernel 2: MFMA flash attention, TQ=64 (512 threads, 8 waves, 1 block/CU).
// Round-3 structure (verified 636 us) + deeper prefetch rings only:
// - V ring 4 -> 8 deep: all 8 j-slots of kc=0 issued right after phase A
//   (covered by the whole softmax section), refilled one kc-block (8 steps)
//   ahead in phase C.
// - K ring 6 -> 8 deep.
// Register-budgeted: +24 arch VGPRs over round 3 (~228 peak of 256 incl.
// 128 accum) -> no spill (tripwire: WRITE_SIZE must stay ~71 MB).
// LDS: Qs 128 KB + Ps 16 KB + wmax/wl 4 KB.
// ---------------------------------------------------------------------------
#define TQ 64
#define TK 128

__global__ __launch_bounds__(512, 2) void flash_attn(
    const half_t* __restrict__ qw, const half_t* __restrict__ kw,
    const half_t* __restrict__ vt, float* __restrict__ out) {
  // batch -> 2 XCDs; 32 blocks/XCD share one K/V stream, 1 block/CU.
  const int slot = blockIdx.x & 7;
  const int b = slot >> 1;
  const int qb = ((blockIdx.x >> 3) << 1) | (slot & 1);
  const int q0 = qb * TQ;
  const int t = threadIdx.x;
  const int w = t >> 6;
  const int lane = t & 63;
  const int ln = lane & 15;
  const int quad = lane >> 4;

  __shared__ half_t Qs[65536];  // [rs(4)][ks(32)][lane(64)][8] = 128 KB
  __shared__ half_t Ps[8192];   // [rs(4)][kc(4)][lane(64)][8] = 16 KB
  __shared__ float wmax[8][64];
  __shared__ float wl[8][64];

  const half_t* qp = qw + ((size_t)b * S_LEN + q0) * H_DIM;
  const half_t* kbp = kw + (size_t)b * S_LEN * H_DIM;
  const half_t* vbt = vt + (size_t)b * H_DIM * S_LEN;

  // K ring prologue for kt=0 (issued before Q staging so it lands early)
  const half_t* kr = kbp + (size_t)(w * 16 + ln) * H_DIM + quad * 8;
  half8_t kbuf[8];
#pragma unroll
  for (int d = 0; d < 8; d++) kbuf[d] = *(const half8_t*)(kr + d * 32);

  // stage Q tile into fragment order
#pragma unroll
  for (int i = 0; i < 16; i++) {
    int flat = t * 8 + i * 4096;
    int r = flat >> 10, c = flat & 1023;
    int rs = r >> 4, lq = r & 15, ks = c >> 5, qd = (c >> 3) & 3;
    *(half8_t*)&Qs[((rs * 32 + ks) * 64 + qd * 16 + lq) * 8] =
        *(const half8_t*)&qp[(size_t)r * H_DIM + c];
  }
  BAR_LDS();

  // per-lane softmax running state, lane <-> q row (all waves redundant)
  float m_l = -1e30f;
  float l_l = 0.0f;

  float4_t O[4][8] = {};  // [rs(4 row-tiles)][j(8 col-tiles in h-chunk w)]

  for (int kt = 0; kt < S_LEN; kt += TK) {
    // ---------------- phase A: S = Q . K^T ----------------
    // wave w: K rows kt + w*16 .. +16 (S-cols of the 128 tile), all 4 Q
    // row-sets; K tile read once per block. kbuf preloaded by prev iter.
    float4_t s[4] = {};
    __builtin_amdgcn_s_setprio(1);
#pragma unroll
    for (int ks = 0; ks < 32; ks++) {
      half8_t a0 = *(const half8_t*)&Qs[(ks * 64 + lane) * 8];
      half8_t a1 = *(const half8_t*)&Qs[16384 + (ks * 64 + lane) * 8];
      half8_t a2 = *(const half8_t*)&Qs[32768 + (ks * 64 + lane) * 8];
      half8_t a3 = *(const half8_t*)&Qs[49152 + (ks * 64 + lane) * 8];
      half8_t kc = kbuf[ks & 7];
      if (ks < 24) kbuf[ks & 7] = *(const half8_t*)(kr + (ks + 8) * 32);
      s[0] = MFMA16(a0, kc, s[0]);
      s[1] = MFMA16(a1, kc, s[1]);
      s[2] = MFMA16(a2, kc, s[2]);
      s[3] = MFMA16(a3, kc, s[3]);
    }
    __builtin_amdgcn_s_setprio(0);

    // V ring preload (all 8 j-slots of kc=0) — issued FIRST (consumed in
    // this iter's phase C), in flight across the whole softmax section
    const half_t* vbase = vbt + (size_t)(w * 128 + ln) * S_LEN + kt + quad * 8;
    half8_t vr[8];
#pragma unroll
    for (int j = 0; j < 8; j++)
      vr[j] = *(const half8_t*)(vbase + (size_t)j * 16 * S_LEN);

    // K prefetch for NEXT tile — consumed next iter, also covered by softmax
    kr += (size_t)TK * H_DIM;
    if (kt + TK < S_LEN) {
#pragma unroll
      for (int d = 0; d < 8; d++) kbuf[d] = *(const half8_t*)(kr + d * 32);
    }

    // ---------------- softmax stats ----------------
    // s[rs][r]: row q = rs*16 + quad*4 + r, col = w*16 + ln.
    float rm[4][4];
#pragma unroll
    for (int rs = 0; rs < 4; rs++)
#pragma unroll
      for (int r = 0; r < 4; r++) rm[rs][r] = s[rs][r];
#pragma unroll
    for (int off = 1; off < 16; off <<= 1)
#pragma unroll
      for (int rs = 0; rs < 4; rs++)
#pragma unroll
        for (int r = 0; r < 4; r++)
          rm[rs][r] = fmaxf(rm[rs][r], __shfl_xor(rm[rs][r], off));
    if (ln == 0)
#pragma unroll
      for (int rs = 0; rs < 4; rs++)
#pragma unroll
        for (int r = 0; r < 4; r++)
          wmax[w][rs * 16 + quad * 4 + r] = rm[rs][r];
    BAR_LDS();  // W1

    // every wave redundantly updates running max for q = lane
    float nm_l = m_l;
#pragma unroll
    for (int w2 = 0; w2 < 8; w2++) nm_l = fmaxf(nm_l, wmax[w2][lane]);
    float aS_l = __expf(m_l - nm_l);
    m_l = nm_l;

    // ---- P = exp(S - m) -> Ps (fragment order), O rescale fused ----
    const int pbase = (w >> 1) * 512 + (w & 1) * 256 + (ln >> 3) * 128 +
                      quad * 32 + (ln & 7);
    float pl[4][4];
#pragma unroll
    for (int rs = 0; rs < 4; rs++)
#pragma unroll
      for (int r = 0; r < 4; r++) {
        const int q = rs * 16 + quad * 4 + r;
        float nmq = __shfl(m_l, q);
        float aq = __shfl(aS_l, q);
        float p = __expf(s[rs][r] - nmq);
        pl[rs][r] = p;
        Ps[pbase + rs * 2048 + r * 8] = (half_t)p;
#pragma unroll
        for (int j = 0; j < 8; j++) O[rs][j][r] *= aq;
      }
#pragma unroll
    for (int off = 1; off < 16; off <<= 1)
#pragma unroll
      for (int rs = 0; rs < 4; rs++)
#pragma unroll
        for (int r = 0; r < 4; r++) pl[rs][r] += __shfl_xor(pl[rs][r], off);
    if (ln == 0)
#pragma unroll
      for (int rs = 0; rs < 4; rs++)
#pragma unroll
        for (int r = 0; r < 4; r++)
          wl[w][rs * 16 + quad * 4 + r] = pl[rs][r];
    BAR_LDS();  // W2

    // every wave redundantly updates running denom for q = lane
    float s8_l = 0.f;
#pragma unroll
    for (int w2 = 0; w2 < 8; w2++) s8_l += wl[w2][lane];
    l_l = l_l * aS_l + s8_l;

    // ---------------- phase C: O += P @ V (kc-major, 8-deep V ring) -------
#pragma unroll
    for (int kc = 0; kc < 4; kc++) {
      half8_t pa[4];
#pragma unroll
      for (int rs = 0; rs < 4; rs++)
        pa[rs] = *(const half8_t*)&Ps[((rs * 4 + kc) * 64 + lane) * 8];
      __builtin_amdgcn_s_setprio(1);
#pragma unroll
      for (int j = 0; j < 8; j++) {
        half8_t vc = vr[j];
        if (kc < 3)
          vr[j] = *(const half8_t*)(vbase + (size_t)j * 16 * S_LEN +
                                    (kc + 1) * 32);
#pragma unroll
        for (int rs = 0; rs < 4; rs++)
          O[rs][j] = MFMA16(pa[rs], vc, O[rs][j]);
      }
      __builtin_amdgcn_s_setprio(0);
    }
  }

  // ---------------- epilogue ----------------
  float il[4][4];
#pragma unroll
  for (int rs = 0; rs < 4; rs++)
#pragma unroll
    for (int r = 0; r < 4; r++)
      il[rs][r] = 1.0f / __shfl(l_l, rs * 16 + quad * 4 + r);
  float* ob = out + ((size_t)b * S_LEN + q0) * H_DIM + w * 128 + ln;
#pragma unroll
  for (int rs = 0; rs < 4; rs++)
#pragma unroll
    for (int j = 0; j < 8; j++)
#pragma unroll
      for (int r = 0; r < 4; r++)
        ob[(size_t)(rs * 16 + quad * 4 + r) * H_DIM + j * 16] =
            O[rs][j][r] * il[rs][r];
}

// ---------------------------------------------------------------------------
extern "C" void kernel_launch(void* const* d_in, const int* in_sizes, int n_in,
                              void* d_out, int out_size, void* d_ws,
                              size_t ws_size, hipStream_t stream) {
  const float* x = (const float*)d_in[0];
  const float* Wq = (const float*)d_in[1];
  const float* bq = (const float*)d_in[2];
  const float* Wk = (const float*)d_in[3];
  const float* bk = (const float*)d_in[4];
  const float* Wv = (const float*)d_in[5];
  const float* bv = (const float*)d_in[6];
  half_t* ws = (half_t*)d_ws;  // q(32MB) | k(32MB) | vt(32MB, transposed)
  float* out = (float*)d_out;

  half_t* wth = (half_t*)d_out;  // scratch; overwritten by flash_attn
  half_t* wtl = wth + (size_t)3 * H_DIM * H_DIM;

  wt_prep<<<dim3(32, 32, 3), 256, 0, stream>>>(Wq, Wk, Wv, wth, wtl);

  qkv_mfma<<<dim3(8, 128, 3), 256, 0, stream>>>(x, wth, wtl, bq, bk, bv, ws);

  const half_t* qw = ws;
  const half_t* kw = ws + (size_t)NB * S_LEN * H_DIM;
  const half_t* vt = ws + 2 * (size_t)NB * S_LEN * H_DIM;
  flash_attn<<<dim3((S_LEN / TQ) * NB), 512, 0, stream>>>(qw, kw, vt, out);
}

// Round 6
// 998.418 us; speedup vs baseline: 1.8829x; 1.1365x over previous
//
#include <hip/hip_runtime.h>

typedef _Float16 half_t;
typedef _Float16 half4_t __attribute__((ext_vector_type(4)));
typedef _Float16 half8_t __attribute__((ext_vector_type(8)));
typedef float float4_t __attribute__((ext_vector_type(4)));

#define S_LEN 4096
#define NB 4
#define H_DIM 1024

#define MFMA16(a, b, c) __builtin_amdgcn_mfma_f32_16x16x32_f16(a, b, c, 0, 0, 0)

// LDS-only barrier (guide-verified m201 pattern): wait local (LDS) ops, then
// the compiler-visible barrier builtin. Global loads stay in flight across it.
#define BAR_LDS()                                      \
  do {                                                 \
    asm volatile("s_waitcnt lgkmcnt(0)" ::: "memory"); \
    __builtin_amdgcn_s_barrier();                      \
  } while (0)

// ---------------------------------------------------------------------------
// Kernel 0: transpose + fp16-split W -> Wt_hi/Wt_lo [h][f] (scratch in d_out;
// flash_attn overwrites all of d_out afterwards).
// ---------------------------------------------------------------------------
__global__ __launch_bounds__(256) void wt_prep(
    const float* __restrict__ Wq, const float* __restrict__ Wk,
    const float* __restrict__ Wv, half_t* __restrict__ wth,
    half_t* __restrict__ wtl) {
  const int zi = blockIdx.z;
  const float* W = (zi == 0) ? Wq : (zi == 1) ? Wk : Wv;
  half_t* oh = wth + (size_t)zi * H_DIM * H_DIM;
  half_t* ol = wtl + (size_t)zi * H_DIM * H_DIM;
  const int h0 = blockIdx.x * 32, f0 = blockIdx.y * 32;
  __shared__ float Ws[32][33];
  const int t = threadIdx.x;
  const int c = t & 31, r8 = t >> 5;
#pragma unroll
  for (int rr = 0; rr < 4; rr++)
    Ws[r8 * 4 + rr][c] = W[(size_t)(f0 + r8 * 4 + rr) * H_DIM + h0 + c];
  __syncthreads();
#pragma unroll
  for (int rr = 0; rr < 4; rr++) {
    int h = r8 * 4 + rr;
    float v = Ws[c][h];
    half_t hi = (half_t)v;
    half_t lo = (half_t)(v - (float)hi);
    oh[(size_t)(h0 + h) * H_DIM + f0 + c] = hi;
    ol[(size_t)(h0 + h) * H_DIM + f0 + c] = lo;
  }
}

// ---------------------------------------------------------------------------
// Kernel 1: QKV projection on MFMA, 3-term fp16 split (hh + lh + hl).
// This round: 256x256 tiles (512 threads, 8 waves, each wave 32h x 256s),
// single dispatch over dim3(12, 64): bx = zi*4 + h-tile, by = s-tile.
// Halves both A(W-split) and B(x) cache traffic vs 128x128 (3 GB -> 1.5 GB,
// the measured qkv bottleneck); natural round-robin dispatch leaves each XCD
// touching only 3 of the 12 one-MB A-panels (gcd(8,12)=4) -> A L2-resident.
// BAR_LDS instead of __syncthreads so A-prefetch survives the stage barrier.
// ---------------------------------------------------------------------------
#define QKV_BK 64

__global__ __launch_bounds__(512, 2) void qkv_mfma(
    const float* __restrict__ x, const half_t* __restrict__ wth,
    const half_t* __restrict__ wtl, const float* __restrict__ bq,
    const float* __restrict__ bk, const float* __restrict__ bv,
    half_t* __restrict__ ws) {
  const int bx = blockIdx.x;      // 0..11 = zi*4 + h-tile
  const int zi = bx >> 2;
  const int m0 = (bx & 3) * 256;  // h-tile base within zi
  const int n0 = blockIdx.y * 256;  // flattened b*s tile base
  const half_t* Ah_g = wth + (size_t)zi * H_DIM * H_DIM;
  const half_t* Al_g = wtl + (size_t)zi * H_DIM * H_DIM;
  const float* bias = (zi == 0) ? bq : (zi == 1) ? bk : bv;
  half_t* out = ws + (size_t)zi * ((size_t)NB * S_LEN * H_DIM);
  const int t = threadIdx.x;
  const int w = t >> 6, lane = t & 63, ln = lane & 15, quad = lane >> 4;

  __shared__ half_t Bs[32768];  // hi[16384] | lo[16384] halves = 64 KB

  float4_t acc[2][16] = {};

  const int ss = t >> 1;        // 0..255: s-row within tile
  const int fh = (t & 1) * 32;  // k-col half
  const int snt = ss >> 4, sln = ss & 15;

  for (int k0 = 0; k0 < H_DIM; k0 += QKV_BK) {
    half8_t ah[2][2], al[2][2];
#pragma unroll
    for (int i = 0; i < 2; i++) {
      const size_t arow =
          (size_t)(m0 + w * 32 + i * 16 + ln) * H_DIM + k0 + quad * 8;
#pragma unroll
      for (int k2 = 0; k2 < 2; k2++) {
        ah[i][k2] = *(const half8_t*)(Ah_g + arow + k2 * 32);
        al[i][k2] = *(const half8_t*)(Al_g + arow + k2 * 32);
      }
    }
    BAR_LDS();  // prior-iter Bs reads done; A loads stay in flight
    {
      const float* xp = x + (size_t)(n0 + ss) * H_DIM + k0 + fh;
#pragma unroll
      for (int g = 0; g < 4; g++) {
        float4 v0 = *(const float4*)(xp + g * 8);
        float4 v1 = *(const float4*)(xp + g * 8 + 4);
        float vv[8] = {v0.x, v0.y, v0.z, v0.w, v1.x, v1.y, v1.z, v1.w};
        half8_t hhi, hlo;
#pragma unroll
        for (int j = 0; j < 8; j++) {
          half_t h = (half_t)vv[j];
          hhi[j] = h;
          hlo[j] = (half_t)(vv[j] - (float)h);
        }
        int f = fh + g * 8;
        int k2 = f >> 5, qd = (f >> 3) & 3;
        int base = ((k2 * 16 + snt) * 64 + qd * 16 + sln) * 8;
        *(half8_t*)&Bs[base] = hhi;
        *(half8_t*)&Bs[16384 + base] = hlo;
      }
    }
    BAR_LDS();
#pragma unroll
    for (int k2 = 0; k2 < 2; k2++) {
#pragma unroll
      for (int nt = 0; nt < 16; nt++) {
        int base = ((k2 * 16 + nt) * 64 + lane) * 8;
        half8_t bh = *(const half8_t*)&Bs[base];
        half8_t bl = *(const half8_t*)&Bs[16384 + base];
        acc[0][nt] = MFMA16(ah[0][k2], bh, acc[0][nt]);
        acc[1][nt] = MFMA16(ah[1][k2], bh, acc[1][nt]);
        acc[0][nt] = MFMA16(al[0][k2], bh, acc[0][nt]);
        acc[1][nt] = MFMA16(al[1][k2], bh, acc[1][nt]);
        acc[0][nt] = MFMA16(ah[0][k2], bl, acc[0][nt]);
        acc[1][nt] = MFMA16(ah[1][k2], bl, acc[1][nt]);
      }
    }
  }

  const float oscale = (zi == 0) ? 0.03125f : 1.0f;
  float bb[2][4];
#pragma unroll
  for (int i = 0; i < 2; i++)
#pragma unroll
    for (int r = 0; r < 4; r++)
      bb[i][r] = bias[m0 + w * 32 + i * 16 + quad * 4 + r];

  if (zi < 2) {
#pragma unroll
    for (int i = 0; i < 2; i++)
#pragma unroll
      for (int nt = 0; nt < 16; nt++) {
        half4_t h4;
#pragma unroll
        for (int r = 0; r < 4; r++)
          h4[r] = (half_t)((acc[i][nt][r] + bb[i][r]) * oscale);
        size_t s = n0 + nt * 16 + ln;
        *(half4_t*)&out[s * H_DIM + m0 + w * 32 + i * 16 + quad * 4] = h4;
      }
  } else {
#pragma unroll
    for (int i = 0; i < 2; i++)
#pragma unroll
      for (int nt = 0; nt < 16; nt++) {
        int sf = n0 + nt * 16 + ln;
        int b = sf >> 12, si = sf & 4095;
#pragma unroll
        for (int r = 0; r < 4; r++) {
          int h = m0 + w * 32 + i * 16 + quad * 4 + r;
          out[((size_t)b * H_DIM + h) * S_LEN + si] =
              (half_t)(acc[i][nt][r] + bb[i][r]);
        }
      }
  }
}

// ---------------------------------------------------------------------------
// Kernel 2: MFMA flash attention, TQ=64 (512 threads, 8 waves, 1 block/CU).
// Round-3 verified version (636 us): LDS-only barriers, per-lane softmax
// state, cross-tile K prefetch (6-deep ring), kc-major phase C (4-deep V
// ring). Round-5's deeper rings regressed (mild spill) — reverted.
// flash_attn is within ~30% of its 8.8 TB/s cache-traffic floor (476 us).
// LDS: Qs 128 KB + Ps 16 KB + wmax/wl 4 KB.
// ---------------------------------------------------------------------------
#define TQ 64
#define TK 128

__global__ __launch_bounds__(512, 2) void flash_attn(
    const half_t* __restrict__ qw, const half_t* __restrict__ kw,
    const half_t* __restrict__ vt, float* __restrict__ out) {
  // batch -> 2 XCDs; 32 blocks/XCD share one K/V stream, 1 block/CU.
  const int slot = blockIdx.x & 7;
  const int b = slot >> 1;
  const int qb = ((blockIdx.x >> 3) << 1) | (slot & 1);
  const int q0 = qb * TQ;
  const int t = threadIdx.x;
  const int w = t >> 6;
  const int lane = t & 63;
  const int ln = lane & 15;
  const int quad = lane >> 4;

  __shared__ half_t Qs[65536];  // [rs(4)][ks(32)][lane(64)][8] = 128 KB
  __shared__ half_t Ps[8192];   // [rs(4)][kc(4)][lane(64)][8] = 16 KB
  __shared__ float wmax[8][64];
  __shared__ float wl[8][64];

  const half_t* qp = qw + ((size_t)b * S_LEN + q0) * H_DIM;
  const half_t* kbp = kw + (size_t)b * S_LEN * H_DIM;
  const half_t* vbt = vt + (size_t)b * H_DIM * S_LEN;

  // K ring prologue for kt=0 (issued before Q staging so it lands early)
  const half_t* kr = kbp + (size_t)(w * 16 + ln) * H_DIM + quad * 8;
  half8_t kbuf[6];
#pragma unroll
  for (int d = 0; d < 6; d++) kbuf[d] = *(const half8_t*)(kr + d * 32);

  // stage Q tile into fragment order
#pragma unroll
  for (int i = 0; i < 16; i++) {
    int flat = t * 8 + i * 4096;
    int r = flat >> 10, c = flat & 1023;
    int rs = r >> 4, lq = r & 15, ks = c >> 5, qd = (c >> 3) & 3;
    *(half8_t*)&Qs[((rs * 32 + ks) * 64 + qd * 16 + lq) * 8] =
        *(const half8_t*)&qp[(size_t)r * H_DIM + c];
  }
  BAR_LDS();

  // per-lane softmax running state, lane <-> q row (all waves redundant)
  float m_l = -1e30f;
  float l_l = 0.0f;

  float4_t O[4][8] = {};  // [rs(4 row-tiles)][j(8 col-tiles in h-chunk w)]

  for (int kt = 0; kt < S_LEN; kt += TK) {
    // ---------------- phase A: S = Q . K^T ----------------
    // wave w: K rows kt + w*16 .. +16 (S-cols of the 128 tile), all 4 Q
    // row-sets; K tile read once per block. kbuf preloaded by prev iter.
    float4_t s[4] = {};
    __builtin_amdgcn_s_setprio(1);
#pragma unroll
    for (int ks = 0; ks < 32; ks++) {
      half8_t a0 = *(const half8_t*)&Qs[(ks * 64 + lane) * 8];
      half8_t a1 = *(const half8_t*)&Qs[16384 + (ks * 64 + lane) * 8];
      half8_t a2 = *(const half8_t*)&Qs[32768 + (ks * 64 + lane) * 8];
      half8_t a3 = *(const half8_t*)&Qs[49152 + (ks * 64 + lane) * 8];
      half8_t kc = kbuf[ks % 6];
      if (ks < 26) kbuf[ks % 6] = *(const half8_t*)(kr + (ks + 6) * 32);
      s[0] = MFMA16(a0, kc, s[0]);
      s[1] = MFMA16(a1, kc, s[1]);
      s[2] = MFMA16(a2, kc, s[2]);
      s[3] = MFMA16(a3, kc, s[3]);
    }
    __builtin_amdgcn_s_setprio(0);

    // K prefetch for NEXT tile — in flight across softmax + phase C
    kr += (size_t)TK * H_DIM;
    if (kt + TK < S_LEN) {
#pragma unroll
      for (int d = 0; d < 6; d++) kbuf[d] = *(const half8_t*)(kr + d * 32);
    }

    // V ring prefetch (j=0..3 of kc=0) — in flight across softmax
    const half_t* vbase = vbt + (size_t)(w * 128 + ln) * S_LEN + kt + quad * 8;
    half8_t vr[4];
#pragma unroll
    for (int j = 0; j < 4; j++)
      vr[j] = *(const half8_t*)(vbase + (size_t)j * 16 * S_LEN);

    // ---------------- softmax stats ----------------
    // s[rs][r]: row q = rs*16 + quad*4 + r, col = w*16 + ln.
    float rm[4][4];
#pragma unroll
    for (int rs = 0; rs < 4; rs++)
#pragma unroll
      for (int r = 0; r < 4; r++) rm[rs][r] = s[rs][r];
#pragma unroll
    for (int off = 1; off < 16; off <<= 1)
#pragma unroll
      for (int rs = 0; rs < 4; rs++)
#pragma unroll
        for (int r = 0; r < 4; r++)
          rm[rs][r] = fmaxf(rm[rs][r], __shfl_xor(rm[rs][r], off));
    if (ln == 0)
#pragma unroll
      for (int rs = 0; rs < 4; rs++)
#pragma unroll
        for (int r = 0; r < 4; r++)
          wmax[w][rs * 16 + quad * 4 + r] = rm[rs][r];
    BAR_LDS();  // W1

    // every wave redundantly updates running max for q = lane
    float nm_l = m_l;
#pragma unroll
    for (int w2 = 0; w2 < 8; w2++) nm_l = fmaxf(nm_l, wmax[w2][lane]);
    float aS_l = __expf(m_l - nm_l);
    m_l = nm_l;

    // ---- P = exp(S - m) -> Ps (fragment order), O rescale fused ----
    const int pbase = (w >> 1) * 512 + (w & 1) * 256 + (ln >> 3) * 128 +
                      quad * 32 + (ln & 7);
    float pl[4][4];
#pragma unroll
    for (int rs = 0; rs < 4; rs++)
#pragma unroll
      for (int r = 0; r < 4; r++) {
        const int q = rs * 16 + quad * 4 + r;
        float nmq = __shfl(m_l, q);
        float aq = __shfl(aS_l, q);
        float p = __expf(s[rs][r] - nmq);
        pl[rs][r] = p;
        Ps[pbase + rs * 2048 + r * 8] = (half_t)p;
#pragma unroll
        for (int j = 0; j < 8; j++) O[rs][j][r] *= aq;
      }
#pragma unroll
    for (int off = 1; off < 16; off <<= 1)
#pragma unroll
      for (int rs = 0; rs < 4; rs++)
#pragma unroll
        for (int r = 0; r < 4; r++) pl[rs][r] += __shfl_xor(pl[rs][r], off);
    if (ln == 0)
#pragma unroll
      for (int rs = 0; rs < 4; rs++)
#pragma unroll
        for (int r = 0; r < 4; r++)
          wl[w][rs * 16 + quad * 4 + r] = pl[rs][r];
    BAR_LDS();  // W2

    // every wave redundantly updates running denom for q = lane
    float s8_l = 0.f;
#pragma unroll
    for (int w2 = 0; w2 < 8; w2++) s8_l += wl[w2][lane];
    l_l = l_l * aS_l + s8_l;

    // ---------------- phase C: O += P @ V (kc-major) ----------------
#pragma unroll
    for (int kc = 0; kc < 4; kc++) {
      half8_t pa[4];
#pragma unroll
      for (int rs = 0; rs < 4; rs++)
        pa[rs] = *(const half8_t*)&Ps[((rs * 4 + kc) * 64 + lane) * 8];
      __builtin_amdgcn_s_setprio(1);
#pragma unroll
      for (int j = 0; j < 8; j++) {
        half8_t vc = vr[j & 3];
        const int jn = j + 4;
        if (jn < 8) {
          vr[j & 3] =
              *(const half8_t*)(vbase + (size_t)jn * 16 * S_LEN + kc * 32);
        } else if (kc < 3) {
          vr[j & 3] = *(const half8_t*)(vbase + (size_t)(jn - 8) * 16 * S_LEN +
                                        (kc + 1) * 32);
        }
#pragma unroll
        for (int rs = 0; rs < 4; rs++)
          O[rs][j] = MFMA16(pa[rs], vc, O[rs][j]);
      }
      __builtin_amdgcn_s_setprio(0);
    }
  }

  // ---------------- epilogue ----------------
  float il[4][4];
#pragma unroll
  for (int rs = 0; rs < 4; rs++)
#pragma unroll
    for (int r = 0; r < 4; r++)
      il[rs][r] = 1.0f / __shfl(l_l, rs * 16 + quad * 4 + r);
  float* ob = out + ((size_t)b * S_LEN + q0) * H_DIM + w * 128 + ln;
#pragma unroll
  for (int rs = 0; rs < 4; rs++)
#pragma unroll
    for (int j = 0; j < 8; j++)
#pragma unroll
      for (int r = 0; r < 4; r++)
        ob[(size_t)(rs * 16 + quad * 4 + r) * H_DIM + j * 16] =
            O[rs][j][r] * il[rs][r];
}

// ---------------------------------------------------------------------------
extern "C" void kernel_launch(void* const* d_in, const int* in_sizes, int n_in,
                              void* d_out, int out_size, void* d_ws,
                              size_t ws_size, hipStream_t stream) {
  const float* x = (const float*)d_in[0];
  const float* Wq = (const float*)d_in[1];
  const float* bq = (const float*)d_in[2];
  const float* Wk = (const float*)d_in[3];
  const float* bk = (const float*)d_in[4];
  const float* Wv = (const float*)d_in[5];
  const float* bv = (const float*)d_in[6];
  half_t* ws = (half_t*)d_ws;  // q(32MB) | k(32MB) | vt(32MB, transposed)
  float* out = (float*)d_out;

  half_t* wth = (half_t*)d_out;  // scratch; overwritten by flash_attn
  half_t* wtl = wth + (size_t)3 * H_DIM * H_DIM;

  wt_prep<<<dim3(32, 32, 3), 256, 0, stream>>>(Wq, Wk, Wv, wth, wtl);

  qkv_mfma<<<dim3(12, 64), 512, 0, stream>>>(x, wth, wtl, bq, bk, bv, ws);

  const half_t* qw = ws;
  const half_t* kw = ws + (size_t)NB * S_LEN * H_DIM;
  const half_t* vt = ws + 2 * (size_t)NB * S_LEN * H_DIM;
  flash_attn<<<dim3((S_LEN / TQ) * NB), 512, 0, stream>>>(qw, kw, vt, out);
}

// Round 7
// 957.423 us; speedup vs baseline: 1.9635x; 1.0428x over previous
//
#include <hip/hip_runtime.h>

typedef _Float16 half_t;
typedef _Float16 half4_t __attribute__((ext_vector_type(4)));
typedef _Float16 half8_t __attribute__((ext_vector_type(8)));
typedef float float4_t __attribute__((ext_vector_type(4)));

#define S_LEN 4096
#define NB 4
#define H_DIM 1024

#define MFMA16(a, b, c) __builtin_amdgcn_mfma_f32_16x16x32_f16(a, b, c, 0, 0, 0)

// LDS-only barrier (guide-verified m201 pattern): wait local (LDS) ops, then
// the compiler-visible barrier builtin. Global loads stay in flight across it.
#define BAR_LDS()                                      \
  do {                                                 \
    asm volatile("s_waitcnt lgkmcnt(0)" ::: "memory"); \
    __builtin_amdgcn_s_barrier();                      \
  } while (0)

// ---------------------------------------------------------------------------
// Kernel 0: transpose + fp16-split W -> Wt_hi/Wt_lo [h][f] (scratch in d_out;
// flash_attn overwrites all of d_out afterwards).
// ---------------------------------------------------------------------------
__global__ __launch_bounds__(256) void wt_prep(
    const float* __restrict__ Wq, const float* __restrict__ Wk,
    const float* __restrict__ Wv, half_t* __restrict__ wth,
    half_t* __restrict__ wtl) {
  const int zi = blockIdx.z;
  const float* W = (zi == 0) ? Wq : (zi == 1) ? Wk : Wv;
  half_t* oh = wth + (size_t)zi * H_DIM * H_DIM;
  half_t* ol = wtl + (size_t)zi * H_DIM * H_DIM;
  const int h0 = blockIdx.x * 32, f0 = blockIdx.y * 32;
  __shared__ float Ws[32][33];
  const int t = threadIdx.x;
  const int c = t & 31, r8 = t >> 5;
#pragma unroll
  for (int rr = 0; rr < 4; rr++)
    Ws[r8 * 4 + rr][c] = W[(size_t)(f0 + r8 * 4 + rr) * H_DIM + h0 + c];
  __syncthreads();
#pragma unroll
  for (int rr = 0; rr < 4; rr++) {
    int h = r8 * 4 + rr;
    float v = Ws[c][h];
    half_t hi = (half_t)v;
    half_t lo = (half_t)(v - (float)hi);
    oh[(size_t)(h0 + h) * H_DIM + f0 + c] = hi;
    ol[(size_t)(h0 + h) * H_DIM + f0 + c] = lo;
  }
}

// ---------------------------------------------------------------------------
// Kernel 1: QKV projection on MFMA, 3-term fp16 split (hh + lh + hl).
// 256x256 tiles (512 threads, 8 waves), dim3(12, 64).
// This round: software pipeline (T3/T14). Bs double-buffered (2x64 KB);
// per iter: issue A-frags(i) + x-regs(i+1) BEFORE the LDS-only barrier
// (globals stay in flight, barrier wait = free cover), MFMA on Bs[cur]
// (hides x(i+1) latency), then convert+write Bs[cur^1]. ONE barrier/iter.
// Race-free: writes target cur^1 only; barrier chain separates write(b)
// from read(b) by a full iteration. Regs ~222 < 256 (no spill budget).
// ---------------------------------------------------------------------------
#define QKV_BK 64

__global__ __launch_bounds__(512, 2) void qkv_mfma(
    const float* __restrict__ x, const half_t* __restrict__ wth,
    const half_t* __restrict__ wtl, const float* __restrict__ bq,
    const float* __restrict__ bk, const float* __restrict__ bv,
    half_t* __restrict__ ws) {
  const int bx = blockIdx.x;        // 0..11 = zi*4 + h-tile
  const int zi = bx >> 2;
  const int m0 = (bx & 3) * 256;    // h-tile base within zi
  const int n0 = blockIdx.y * 256;  // flattened b*s tile base
  const half_t* Ah_g = wth + (size_t)zi * H_DIM * H_DIM;
  const half_t* Al_g = wtl + (size_t)zi * H_DIM * H_DIM;
  const float* bias = (zi == 0) ? bq : (zi == 1) ? bk : bv;
  half_t* out = ws + (size_t)zi * ((size_t)NB * S_LEN * H_DIM);
  const int t = threadIdx.x;
  const int w = t >> 6, lane = t & 63, ln = lane & 15, quad = lane >> 4;

  __shared__ half_t Bs[2][32768];  // per buf: hi[16384] | lo[16384] = 64 KB

  float4_t acc[2][16] = {};

  const int ss = t >> 1;        // 0..255: s-row within tile
  const int fh = (t & 1) * 32;  // k-col half
  const int snt = ss >> 4, sln = ss & 15;

  const float* xrow = x + (size_t)(n0 + ss) * H_DIM + fh;

  // ---- prologue: load x(0), convert, write Bs[0] ----
  float4 xr[8];
#pragma unroll
  for (int g = 0; g < 4; g++) {
    xr[2 * g] = *(const float4*)(xrow + g * 8);
    xr[2 * g + 1] = *(const float4*)(xrow + g * 8 + 4);
  }
#pragma unroll
  for (int g = 0; g < 4; g++) {
    float vv[8] = {xr[2 * g].x,     xr[2 * g].y,     xr[2 * g].z,
                   xr[2 * g].w,     xr[2 * g + 1].x, xr[2 * g + 1].y,
                   xr[2 * g + 1].z, xr[2 * g + 1].w};
    half8_t hhi, hlo;
#pragma unroll
    for (int j = 0; j < 8; j++) {
      half_t h = (half_t)vv[j];
      hhi[j] = h;
      hlo[j] = (half_t)(vv[j] - (float)h);
    }
    int f = fh + g * 8;
    int k2 = f >> 5, qd = (f >> 3) & 3;
    int base = ((k2 * 16 + snt) * 64 + qd * 16 + sln) * 8;
    *(half8_t*)&Bs[0][base] = hhi;
    *(half8_t*)&Bs[0][16384 + base] = hlo;
  }

  for (int it = 0; it < 16; it++) {
    const int k0 = it * QKV_BK;
    const int cur = it & 1;
    const bool more = (it < 15);

    // issue A-frags(it) — consumed in MFMA right after the barrier
    half8_t ah[2][2], al[2][2];
#pragma unroll
    for (int i = 0; i < 2; i++) {
      const size_t arow =
          (size_t)(m0 + w * 32 + i * 16 + ln) * H_DIM + k0 + quad * 8;
#pragma unroll
      for (int k2 = 0; k2 < 2; k2++) {
        ah[i][k2] = *(const half8_t*)(Ah_g + arow + k2 * 32);
        al[i][k2] = *(const half8_t*)(Al_g + arow + k2 * 32);
      }
    }
    // issue x(it+1) — consumed after MFMA (full-MFMA cover)
    if (more) {
      const float* xp = xrow + (k0 + QKV_BK);
#pragma unroll
      for (int g = 0; g < 4; g++) {
        xr[2 * g] = *(const float4*)(xp + g * 8);
        xr[2 * g + 1] = *(const float4*)(xp + g * 8 + 4);
      }
    }

    BAR_LDS();  // Bs[cur] complete (all waves); globals stay in flight

#pragma unroll
    for (int k2 = 0; k2 < 2; k2++) {
#pragma unroll
      for (int nt = 0; nt < 16; nt++) {
        int base = ((k2 * 16 + nt) * 64 + lane) * 8;
        half8_t bh = *(const half8_t*)&Bs[cur][base];
        half8_t bl = *(const half8_t*)&Bs[cur][16384 + base];
        acc[0][nt] = MFMA16(ah[0][k2], bh, acc[0][nt]);
        acc[1][nt] = MFMA16(ah[1][k2], bh, acc[1][nt]);
        acc[0][nt] = MFMA16(al[0][k2], bh, acc[0][nt]);
        acc[1][nt] = MFMA16(al[1][k2], bh, acc[1][nt]);
        acc[0][nt] = MFMA16(ah[0][k2], bl, acc[0][nt]);
        acc[1][nt] = MFMA16(ah[1][k2], bl, acc[1][nt]);
      }
    }

    // convert + write next buffer (x loads covered by the MFMA block above)
    if (more) {
#pragma unroll
      for (int g = 0; g < 4; g++) {
        float vv[8] = {xr[2 * g].x,     xr[2 * g].y,     xr[2 * g].z,
                       xr[2 * g].w,     xr[2 * g + 1].x, xr[2 * g + 1].y,
                       xr[2 * g + 1].z, xr[2 * g + 1].w};
        half8_t hhi, hlo;
#pragma unroll
        for (int j = 0; j < 8; j++) {
          half_t h = (half_t)vv[j];
          hhi[j] = h;
          hlo[j] = (half_t)(vv[j] - (float)h);
        }
        int f = fh + g * 8;
        int k2 = f >> 5, qd = (f >> 3) & 3;
        int base = ((k2 * 16 + snt) * 64 + qd * 16 + sln) * 8;
        *(half8_t*)&Bs[cur ^ 1][base] = hhi;
        *(half8_t*)&Bs[cur ^ 1][16384 + base] = hlo;
      }
    }
  }

  const float oscale = (zi == 0) ? 0.03125f : 1.0f;
  float bb[2][4];
#pragma unroll
  for (int i = 0; i < 2; i++)
#pragma unroll
    for (int r = 0; r < 4; r++)
      bb[i][r] = bias[m0 + w * 32 + i * 16 + quad * 4 + r];

  if (zi < 2) {
#pragma unroll
    for (int i = 0; i < 2; i++)
#pragma unroll
      for (int nt = 0; nt < 16; nt++) {
        half4_t h4;
#pragma unroll
        for (int r = 0; r < 4; r++)
          h4[r] = (half_t)((acc[i][nt][r] + bb[i][r]) * oscale);
        size_t s = n0 + nt * 16 + ln;
        *(half4_t*)&out[s * H_DIM + m0 + w * 32 + i * 16 + quad * 4] = h4;
      }
  } else {
#pragma unroll
    for (int i = 0; i < 2; i++)
#pragma unroll
      for (int nt = 0; nt < 16; nt++) {
        int sf = n0 + nt * 16 + ln;
        int b = sf >> 12, si = sf & 4095;
#pragma unroll
        for (int r = 0; r < 4; r++) {
          int h = m0 + w * 32 + i * 16 + quad * 4 + r;
          out[((size_t)b * H_DIM + h) * S_LEN + si] =
              (half_t)(acc[i][nt][r] + bb[i][r]);
        }
      }
  }
}

// ---------------------------------------------------------------------------
// Kernel 2: MFMA flash attention, TQ=64 (512 threads, 8 waves, 1 block/CU).
// Round-3 verified version (635 us, reproduced twice): LDS-only barriers,
// per-lane softmax state, cross-tile K prefetch (6-deep ring), kc-major
// phase C (4-deep V ring). FROZEN this round to isolate the qkv change.
// LDS: Qs 128 KB + Ps 16 KB + wmax/wl 4 KB.
// ---------------------------------------------------------------------------
#define TQ 64
#define TK 128

__global__ __launch_bounds__(512, 2) void flash_attn(
    const half_t* __restrict__ qw, const half_t* __restrict__ kw,
    const half_t* __restrict__ vt, float* __restrict__ out) {
  // batch -> 2 XCDs; 32 blocks/XCD share one K/V stream, 1 block/CU.
  const int slot = blockIdx.x & 7;
  const int b = slot >> 1;
  const int qb = ((blockIdx.x >> 3) << 1) | (slot & 1);
  const int q0 = qb * TQ;
  const int t = threadIdx.x;
  const int w = t >> 6;
  const int lane = t & 63;
  const int ln = lane & 15;
  const int quad = lane >> 4;

  __shared__ half_t Qs[65536];  // [rs(4)][ks(32)][lane(64)][8] = 128 KB
  __shared__ half_t Ps[8192];   // [rs(4)][kc(4)][lane(64)][8] = 16 KB
  __shared__ float wmax[8][64];
  __shared__ float wl[8][64];

  const half_t* qp = qw + ((size_t)b * S_LEN + q0) * H_DIM;
  const half_t* kbp = kw + (size_t)b * S_LEN * H_DIM;
  const half_t* vbt = vt + (size_t)b * H_DIM * S_LEN;

  // K ring prologue for kt=0 (issued before Q staging so it lands early)
  const half_t* kr = kbp + (size_t)(w * 16 + ln) * H_DIM + quad * 8;
  half8_t kbuf[6];
#pragma unroll
  for (int d = 0; d < 6; d++) kbuf[d] = *(const half8_t*)(kr + d * 32);

  // stage Q tile into fragment order
#pragma unroll
  for (int i = 0; i < 16; i++) {
    int flat = t * 8 + i * 4096;
    int r = flat >> 10, c = flat & 1023;
    int rs = r >> 4, lq = r & 15, ks = c >> 5, qd = (c >> 3) & 3;
    *(half8_t*)&Qs[((rs * 32 + ks) * 64 + qd * 16 + lq) * 8] =
        *(const half8_t*)&qp[(size_t)r * H_DIM + c];
  }
  BAR_LDS();

  // per-lane softmax running state, lane <-> q row (all waves redundant)
  float m_l = -1e30f;
  float l_l = 0.0f;

  float4_t O[4][8] = {};  // [rs(4 row-tiles)][j(8 col-tiles in h-chunk w)]

  for (int kt = 0; kt < S_LEN; kt += TK) {
    // ---------------- phase A: S = Q . K^T ----------------
    // wave w: K rows kt + w*16 .. +16 (S-cols of the 128 tile), all 4 Q
    // row-sets; K tile read once per block. kbuf preloaded by prev iter.
    float4_t s[4] = {};
    __builtin_amdgcn_s_setprio(1);
#pragma unroll
    for (int ks = 0; ks < 32; ks++) {
      half8_t a0 = *(const half8_t*)&Qs[(ks * 64 + lane) * 8];
      half8_t a1 = *(const half8_t*)&Qs[16384 + (ks * 64 + lane) * 8];
      half8_t a2 = *(const half8_t*)&Qs[32768 + (ks * 64 + lane) * 8];
      half8_t a3 = *(const half8_t*)&Qs[49152 + (ks * 64 + lane) * 8];
      half8_t kc = kbuf[ks % 6];
      if (ks < 26) kbuf[ks % 6] = *(const half8_t*)(kr + (ks + 6) * 32);
      s[0] = MFMA16(a0, kc, s[0]);
      s[1] = MFMA16(a1, kc, s[1]);
      s[2] = MFMA16(a2, kc, s[2]);
      s[3] = MFMA16(a3, kc, s[3]);
    }
    __builtin_amdgcn_s_setprio(0);

    // K prefetch for NEXT tile — in flight across softmax + phase C
    kr += (size_t)TK * H_DIM;
    if (kt + TK < S_LEN) {
#pragma unroll
      for (int d = 0; d < 6; d++) kbuf[d] = *(const half8_t*)(kr + d * 32);
    }

    // V ring prefetch (j=0..3 of kc=0) — in flight across softmax
    const half_t* vbase = vbt + (size_t)(w * 128 + ln) * S_LEN + kt + quad * 8;
    half8_t vr[4];
#pragma unroll
    for (int j = 0; j < 4; j++)
      vr[j] = *(const half8_t*)(vbase + (size_t)j * 16 * S_LEN);

    // ---------------- softmax stats ----------------
    // s[rs][r]: row q = rs*16 + quad*4 + r, col = w*16 + ln.
    float rm[4][4];
#pragma unroll
    for (int rs = 0; rs < 4; rs++)
#pragma unroll
      for (int r = 0; r < 4; r++) rm[rs][r] = s[rs][r];
#pragma unroll
    for (int off = 1; off < 16; off <<= 1)
#pragma unroll
      for (int rs = 0; rs < 4; rs++)
#pragma unroll
        for (int r = 0; r < 4; r++)
          rm[rs][r] = fmaxf(rm[rs][r], __shfl_xor(rm[rs][r], off));
    if (ln == 0)
#pragma unroll
      for (int rs = 0; rs < 4; rs++)
#pragma unroll
        for (int r = 0; r < 4; r++)
          wmax[w][rs * 16 + quad * 4 + r] = rm[rs][r];
    BAR_LDS();  // W1

    // every wave redundantly updates running max for q = lane
    float nm_l = m_l;
#pragma unroll
    for (int w2 = 0; w2 < 8; w2++) nm_l = fmaxf(nm_l, wmax[w2][lane]);
    float aS_l = __expf(m_l - nm_l);
    m_l = nm_l;

    // ---- P = exp(S - m) -> Ps (fragment order), O rescale fused ----
    const int pbase = (w >> 1) * 512 + (w & 1) * 256 + (ln >> 3) * 128 +
                      quad * 32 + (ln & 7);
    float pl[4][4];
#pragma unroll
    for (int rs = 0; rs < 4; rs++)
#pragma unroll
      for (int r = 0; r < 4; r++) {
        const int q = rs * 16 + quad * 4 + r;
        float nmq = __shfl(m_l, q);
        float aq = __shfl(aS_l, q);
        float p = __expf(s[rs][r] - nmq);
        pl[rs][r] = p;
        Ps[pbase + rs * 2048 + r * 8] = (half_t)p;
#pragma unroll
        for (int j = 0; j < 8; j++) O[rs][j][r] *= aq;
      }
#pragma unroll
    for (int off = 1; off < 16; off <<= 1)
#pragma unroll
      for (int rs = 0; rs < 4; rs++)
#pragma unroll
        for (int r = 0; r < 4; r++) pl[rs][r] += __shfl_xor(pl[rs][r], off);
    if (ln == 0)
#pragma unroll
      for (int rs = 0; rs < 4; rs++)
#pragma unroll
        for (int r = 0; r < 4; r++)
          wl[w][rs * 16 + quad * 4 + r] = pl[rs][r];
    BAR_LDS();  // W2

    // every wave redundantly updates running denom for q = lane
    float s8_l = 0.f;
#pragma unroll
    for (int w2 = 0; w2 < 8; w2++) s8_l += wl[w2][lane];
    l_l = l_l * aS_l + s8_l;

    // ---------------- phase C: O += P @ V (kc-major) ----------------
#pragma unroll
    for (int kc = 0; kc < 4; kc++) {
      half8_t pa[4];
#pragma unroll
      for (int rs = 0; rs < 4; rs++)
        pa[rs] = *(const half8_t*)&Ps[((rs * 4 + kc) * 64 + lane) * 8];
      __builtin_amdgcn_s_setprio(1);
#pragma unroll
      for (int j = 0; j < 8; j++) {
        half8_t vc = vr[j & 3];
        const int jn = j + 4;
        if (jn < 8) {
          vr[j & 3] =
              *(const half8_t*)(vbase + (size_t)jn * 16 * S_LEN + kc * 32);
        } else if (kc < 3) {
          vr[j & 3] = *(const half8_t*)(vbase + (size_t)(jn - 8) * 16 * S_LEN +
                                        (kc + 1) * 32);
        }
#pragma unroll
        for (int rs = 0; rs < 4; rs++)
          O[rs][j] = MFMA16(pa[rs], vc, O[rs][j]);
      }
      __builtin_amdgcn_s_setprio(0);
    }
  }

  // ---------------- epilogue ----------------
  float il[4][4];
#pragma unroll
  for (int rs = 0; rs < 4; rs++)
#pragma unroll
    for (int r = 0; r < 4; r++)
      il[rs][r] = 1.0f / __shfl(l_l, rs * 16 + quad * 4 + r);
  float* ob = out + ((size_t)b * S_LEN + q0) * H_DIM + w * 128 + ln;
#pragma unroll
  for (int rs = 0; rs < 4; rs++)
#pragma unroll
    for (int j = 0; j < 8; j++)
#pragma unroll
      for (int r = 0; r < 4; r++)
        ob[(size_t)(rs * 16 + quad * 4 + r) * H_DIM + j * 16] =
            O[rs][j][r] * il[rs][r];
}

// ---------------------------------------------------------------------------
extern "C" void kernel_launch(void* const* d_in, const int* in_sizes, int n_in,
                              void* d_out, int out_size, void* d_ws,
                              size_t ws_size, hipStream_t stream) {
  const float* x = (const float*)d_in[0];
  const float* Wq = (const float*)d_in[1];
  const float* bq = (const float*)d_in[2];
  const float* Wk = (const float*)d_in[3];
  const float* bk = (const float*)d_in[4];
  const float* Wv = (const float*)d_in[5];
  const float* bv = (const float*)d_in[6];
  half_t* ws = (half_t*)d_ws;  // q(32MB) | k(32MB) | vt(32MB, transposed)
  float* out = (float*)d_out;

  half_t* wth = (half_t*)d_out;  // scratch; overwritten by flash_attn
  half_t* wtl = wth + (size_t)3 * H_DIM * H_DIM;

  wt_prep<<<dim3(32, 32, 3), 256, 0, stream>>>(Wq, Wk, Wv, wth, wtl);

  qkv_mfma<<<dim3(12, 64), 512, 0, stream>>>(x, wth, wtl, bq, bk, bv, ws);

  const half_t* qw = ws;
  const half_t* kw = ws + (size_t)NB * S_LEN * H_DIM;
  const half_t* vt = ws + 2 * (size_t)NB * S_LEN * H_DIM;
  flash_attn<<<dim3((S_LEN / TQ) * NB), 512, 0, stream>>>(qw, kw, vt, out);
}